// Round 1
// baseline (68331.921 us; speedup 1.0000x reference)
//
#include <hip/hip_runtime.h>

#define T_LEN 2048
#define G_N   24
#define V_N   2048
#define K_N   512

// ---- rnn_single weight tiers (k-rows per 128-row quarter) ----
// regs: kk in [0,36)  -> Wreg, 144 VGPR/thread
// LDS : kk in [36,40) -> 32 KB
// L2  : kk in [40,128) -> streamed every step, 704 KB/CU/step (stays L2-hot)
#define RREG 36
#define RLDS 4
#define NCHUNK 32          // 128 k-rows / 4 per float4-of-h
#define SCH0 10            // first streamed chunk (kk=40)
#define LOOK 3             // stream lookahead chunks (12 loads in flight/thread)

// ---------------- workspace layout (bytes) ----------------
#define TOK_OFF    4096
#define ROWS_OFF   16384
#define P_OFF      524288

// ---- phase 0: recover tokens from one-hot rows (exactly one 1.0 per row) ----
__global__ void tok_kernel(const float* __restrict__ seq, int* __restrict__ tokens) {
    int wid  = (blockIdx.x * blockDim.x + threadIdx.x) >> 6;   // one wave per row t
    int lane = threadIdx.x & 63;
    if (wid >= T_LEN) return;
    const float* row = seq + (size_t)wid * V_N;
    for (int i = lane; i < V_N; i += 64) {
        if (row[i] > 0.5f) tokens[wid] = i;   // exactly one lane hits: race-free
    }
}

// ---- phase 1: rows[g][t] = perms[g][token[t]] ----
__global__ void rows_kernel(const int* __restrict__ tokens, const int* __restrict__ perms,
                            int* __restrict__ rows) {
    int idx = blockIdx.x * blockDim.x + threadIdx.x;   // g*T + t
    if (idx >= G_N * T_LEN) return;
    int g = idx / T_LEN, t = idx - g * T_LEN;
    rows[idx] = perms[g * V_N + tokens[t]];
}

// ---- phase 2: P = W_e @ Wx + b  (2048x512 @ 512x512, f32 vector GEMM) ----
__global__ __launch_bounds__(256) void pgemm_kernel(const float* __restrict__ We,
                                                    const float* __restrict__ Wx,
                                                    const float* __restrict__ b,
                                                    float* __restrict__ P) {
    __shared__ float As[16][72];   // [k][v], padded
    __shared__ float Bs[16][68];   // [k][j], padded (68 keeps float4 alignment)
    int tid = threadIdx.x;
    int bx = blockIdx.x & 7;        // j tile (K_N/64 = 8)
    int by = blockIdx.x >> 3;       // v tile (V_N/64 = 32)
    int tx = tid & 15, ty = tid >> 4;
    int v0 = by * 64, j0 = bx * 64;
    float acc[4][4] = {};
    for (int k0 = 0; k0 < K_N; k0 += 16) {
        int ar = tid >> 2;            // 0..63
        int ac = (tid & 3) << 2;      // 0,4,8,12
        float4 av = *(const float4*)(We + (size_t)(v0 + ar) * K_N + k0 + ac);
        As[ac + 0][ar] = av.x; As[ac + 1][ar] = av.y;
        As[ac + 2][ar] = av.z; As[ac + 3][ar] = av.w;
        int br = tid >> 4;            // 0..15
        int bc = (tid & 15) << 2;     // 0..60
        float4 bv = *(const float4*)(Wx + (size_t)(k0 + br) * K_N + j0 + bc);
        *(float4*)&Bs[br][bc] = bv;
        __syncthreads();
#pragma unroll
        for (int kk = 0; kk < 16; kk++) {
            float a0 = As[kk][ty * 4 + 0], a1 = As[kk][ty * 4 + 1];
            float a2 = As[kk][ty * 4 + 2], a3 = As[kk][ty * 4 + 3];
            float4 bb = *(const float4*)&Bs[kk][tx * 4];
            acc[0][0] += a0 * bb.x; acc[0][1] += a0 * bb.y; acc[0][2] += a0 * bb.z; acc[0][3] += a0 * bb.w;
            acc[1][0] += a1 * bb.x; acc[1][1] += a1 * bb.y; acc[1][2] += a1 * bb.z; acc[1][3] += a1 * bb.w;
            acc[2][0] += a2 * bb.x; acc[2][1] += a2 * bb.y; acc[2][2] += a2 * bb.z; acc[2][3] += a2 * bb.w;
            acc[3][0] += a3 * bb.x; acc[3][1] += a3 * bb.y; acc[3][2] += a3 * bb.z; acc[3][3] += a3 * bb.w;
        }
        __syncthreads();
    }
    float4 bb = *(const float4*)(b + j0 + tx * 4);
#pragma unroll
    for (int i = 0; i < 4; i++) {
        float4 r;
        r.x = acc[i][0] + bb.x; r.y = acc[i][1] + bb.y;
        r.z = acc[i][2] + bb.z; r.w = acc[i][3] + bb.w;
        *(float4*)(P + (size_t)(v0 + ty * 4 + i) * K_N + j0 + tx * 4) = r;
    }
}

// ---- phase 3: single-workgroup-per-chain RNN (NO inter-WG sync) ----
// 48 blocks x 512 threads; block = (g, dir). Thread (q = tid>>7, c = tid&127)
// owns columns {4c..4c+3} over k-quarter [128q, 128q+128). Per k-row one
// float4 of Wh gives the 4 columns' weights -> all weight traffic (reg fill,
// LDS fill, per-step L2 stream) is coalesced dwordx4 from row-major Wh.
// h broadcast via uniform-address LDS float4 reads (bank-free).
// Numerics mimic the previous (passing) kernel exactly: mod-4 accumulators
// per column, (a0+a1)+(a2+a3), quarters reduced p0+p1+p2+p3, z = xv + sum,
// clamp +-15, tanh via __expf(2z).
__global__ __launch_bounds__(512, 2) void rnn_single(
    const float* __restrict__ P, const float* __restrict__ Wh,
    const int* __restrict__ rows, float* __restrict__ out) {

    __shared__ __align__(16) float  lds_h[K_N];                 // 2 KB
    __shared__ __align__(16) float4 Wlds4[RLDS * 512];          // 32 KB: [e][tid]
    __shared__ __align__(16) float4 partial4[4 * 128];          // 8 KB: [q][c]

    const int tid = threadIdx.x;
    const int q   = tid >> 7;          // k-quarter
    const int c   = tid & 127;         // column group (cols 4c..4c+3)
    const int kb  = q << 7;            // k base
    const int g   = blockIdx.x >> 1;
    const int dir = blockIdx.x & 1;

    const float4* __restrict__ Wh4 = (const float4*)Wh;
    const float4* __restrict__ wbase = Wh4 + (size_t)kb * 128 + c;  // row stride 128 f4

    // one-time register tier fill (coalesced)
    float4 Wreg[RREG];
#pragma unroll
    for (int kk = 0; kk < RREG; kk++)
        Wreg[kk] = wbase[(size_t)kk * 128];
    // one-time LDS tier fill
#pragma unroll
    for (int e = 0; e < RLDS; e++)
        Wlds4[e * 512 + tid] = wbase[(size_t)(RREG + e) * 128];

    lds_h[tid] = 0.f;

    const int* __restrict__ myrows = rows + g * T_LEN;
    // x prefetch for s=0; row prefetch for s=1
    int t0 = (dir == 0) ? 0 : (T_LEN - 2);
    float xv = P[(size_t)myrows[t0] * K_N + tid];
    int t1 = (dir == 0) ? 1 : (T_LEN - 3);
    int rnxt = myrows[t1];

    const size_t outbase = (size_t)g * 1024 + (size_t)dir * 512 + tid;
    float h_prev = 0.f;
    size_t prev_addr = 0;

    __syncthreads();

    for (int s = 0; s < T_LEN; s++) {
        // staggered out-store of previous step's h: its write-ack drains at the
        // NEXT barrier, ~2500cy later -> off the critical path.
        if (s > 0) __builtin_nontemporal_store(h_prev, &out[prev_addr]);
        // prefetch x for s+1 (row preloaded), and row index for s+2
        float xv_next = 0.f;
        if (s + 1 < T_LEN)
            xv_next = P[(size_t)rnxt * K_N + tid];
        if (s + 2 < T_LEN) {
            int sn = s + 2;
            int tn = (dir == 0) ? sn : ((sn == T_LEN - 1) ? (T_LEN - 1) : (T_LEN - 2 - sn));
            rnxt = myrows[tn];
        }

        const float4* __restrict__ h4 = (const float4*)(lds_h + kb);  // wave-uniform
        float4 accA = {0,0,0,0}, accB = {0,0,0,0}, accC = {0,0,0,0}, accD = {0,0,0,0};
        float4 stg[NCHUNK][4];   // compile-time-indexed only -> stays in VGPRs

        // stream prologue: chunks SCH0 .. SCH0+LOOK-1 issued before any FMA;
        // their latency hides under the register-tier chunks 0..8.
#pragma unroll
        for (int i = SCH0; i < SCH0 + LOOK; i++) {
#pragma unroll
            for (int e = 0; e < 4; e++)
                stg[i][e] = wbase[(size_t)(4 * i + e) * 128];
        }
#pragma unroll
        for (int i = 0; i < NCHUNK; i++) {
            // steady-state stream: keep LOOK chunks (12 dwordx4/thread) in flight
            if (i >= SCH0 && i + LOOK < NCHUNK) {
#pragma unroll
                for (int e = 0; e < 4; e++)
                    stg[i + LOOK][e] = wbase[(size_t)(4 * (i + LOOK) + e) * 128];
            }
            float4 hv = h4[i];   // uniform address -> LDS broadcast, conflict-free
            float4 w0, w1, w2, w3;
            if (i < SCH0 - 1) {            // register tier: kk = 4i..4i+3 < 36
                w0 = Wreg[4 * i + 0]; w1 = Wreg[4 * i + 1];
                w2 = Wreg[4 * i + 2]; w3 = Wreg[4 * i + 3];
            } else if (i == SCH0 - 1) {    // LDS tier: kk = 36..39
                w0 = Wlds4[0 * 512 + tid]; w1 = Wlds4[1 * 512 + tid];
                w2 = Wlds4[2 * 512 + tid]; w3 = Wlds4[3 * 512 + tid];
            } else {                       // streamed tier: kk = 40..127
                w0 = stg[i][0]; w1 = stg[i][1]; w2 = stg[i][2]; w3 = stg[i][3];
            }
            accA.x += hv.x * w0.x; accA.y += hv.x * w0.y; accA.z += hv.x * w0.z; accA.w += hv.x * w0.w;
            accB.x += hv.y * w1.x; accB.y += hv.y * w1.y; accB.z += hv.y * w1.z; accB.w += hv.y * w1.w;
            accC.x += hv.z * w2.x; accC.y += hv.z * w2.y; accC.z += hv.z * w2.z; accC.w += hv.z * w2.w;
            accD.x += hv.w * w3.x; accD.y += hv.w * w3.y; accD.z += hv.w * w3.z; accD.w += hv.w * w3.w;
        }
        float4 res;
        res.x = (accA.x + accB.x) + (accC.x + accD.x);
        res.y = (accA.y + accB.y) + (accC.y + accD.y);
        res.z = (accA.z + accB.z) + (accC.z + accD.z);
        res.w = (accA.w + accB.w) + (accC.w + accD.w);
        partial4[(q << 7) + c] = res;      // 16B/lane, consecutive -> conflict-free
        __syncthreads();                   // A

        // reduce: thread tid owns column j = tid
        const float* pf = (const float*)partial4;
        float p0 = pf[0 * 512 + tid], p1 = pf[1 * 512 + tid];
        float p2 = pf[2 * 512 + tid], p3 = pf[3 * 512 + tid];
        float sum = p0 + p1 + p2 + p3;
        float z = xv + sum;
        z = fminf(15.f, fmaxf(-15.f, z));
        float e2 = __expf(2.f * z);
        float h1 = 1.f - 2.f / (e2 + 1.f);                 // tanh(z)
        xv = xv_next;

        int tphys = (dir == 0) ? s : ((s == T_LEN - 1) ? (T_LEN - 1) : (T_LEN - 2 - s));
        prev_addr = (size_t)tphys * (G_N * 1024) + outbase;
        h_prev = h1;
        if (s == T_LEN - 1) break;
        lds_h[tid] = h1;                   // old h fully consumed before barrier A
        __syncthreads();                   // B: h_s visible for next step
    }
    __builtin_nontemporal_store(h_prev, &out[prev_addr]);
    __builtin_nontemporal_store(h_prev, &out[(size_t)T_LEN * (G_N * 1024) + outbase]);
}

extern "C" void kernel_launch(void* const* d_in, const int* in_sizes, int n_in,
                              void* d_out, int out_size, void* d_ws, size_t ws_size,
                              hipStream_t stream) {
    const float* seq   = (const float*)d_in[0];
    const int*   perms = (const int*)d_in[1];
    const float* We    = (const float*)d_in[2];
    const float* Wx    = (const float*)d_in[3];
    const float* Wh    = (const float*)d_in[4];
    const float* b     = (const float*)d_in[5];
    float* out = (float*)d_out;
    char* ws = (char*)d_ws;

    int*   tokens = (int*)(ws + TOK_OFF);
    int*   rows   = (int*)(ws + ROWS_OFF);
    float* P      = (float*)(ws + P_OFF);

    tok_kernel<<<512, 256, 0, stream>>>(seq, tokens);
    rows_kernel<<<(G_N * T_LEN + 255) / 256, 256, 0, stream>>>(tokens, perms, rows);
    pgemm_kernel<<<256, 256, 0, stream>>>(We, Wx, b, P);
    rnn_single<<<G_N * 2, 512, 0, stream>>>(P, Wh, rows, out);
}

// Round 2
// 32460.596 us; speedup vs baseline: 2.1051x; 2.1051x over previous
//
#include <hip/hip_runtime.h>

#define T_LEN 2048
#define G_N   24
#define V_N   2048
#define K_N   512

// ---- rnn_single weight tiers (32 chunks of 4 k-rows per 128-row quarter) ----
// chunks [0,NREGC)        -> registers   (28 rows, 112 VGPR/thread)
// chunks [NREGC,SCH0)     -> LDS         (16 rows, 128 KB)
// chunks [SCH0,32)        -> streamed from L2 every step through a 4-chunk
//                            sliding window (float4 stg[4][4] = 64 VGPR, all
//                            indices compile-time after full unroll; the R1
//                            failure was stg[32][4] = 2KB/thread -> scratch)
#define NREGC 7
#define NLDSC 4
#define SCH0  (NREGC + NLDSC)   // 11
#define NCHUNK 32
#define LOOK 4

// ---------------- workspace layout (bytes) ----------------
#define TOK_OFF    4096
#define ROWS_OFF   16384
#define P_OFF      524288

// ---- phase 0: recover tokens from one-hot rows (exactly one 1.0 per row) ----
__global__ void tok_kernel(const float* __restrict__ seq, int* __restrict__ tokens) {
    int wid  = (blockIdx.x * blockDim.x + threadIdx.x) >> 6;   // one wave per row t
    int lane = threadIdx.x & 63;
    if (wid >= T_LEN) return;
    const float* row = seq + (size_t)wid * V_N;
    for (int i = lane; i < V_N; i += 64) {
        if (row[i] > 0.5f) tokens[wid] = i;   // exactly one lane hits: race-free
    }
}

// ---- phase 1: rows[g][t] = perms[g][token[t]] ----
__global__ void rows_kernel(const int* __restrict__ tokens, const int* __restrict__ perms,
                            int* __restrict__ rows) {
    int idx = blockIdx.x * blockDim.x + threadIdx.x;   // g*T + t
    if (idx >= G_N * T_LEN) return;
    int g = idx / T_LEN, t = idx - g * T_LEN;
    rows[idx] = perms[g * V_N + tokens[t]];
}

// ---- phase 2: P = W_e @ Wx + b  (2048x512 @ 512x512, f32 vector GEMM) ----
__global__ __launch_bounds__(256) void pgemm_kernel(const float* __restrict__ We,
                                                    const float* __restrict__ Wx,
                                                    const float* __restrict__ b,
                                                    float* __restrict__ P) {
    __shared__ float As[16][72];   // [k][v], padded
    __shared__ float Bs[16][68];   // [k][j], padded (68 keeps float4 alignment)
    int tid = threadIdx.x;
    int bx = blockIdx.x & 7;        // j tile (K_N/64 = 8)
    int by = blockIdx.x >> 3;       // v tile (V_N/64 = 32)
    int tx = tid & 15, ty = tid >> 4;
    int v0 = by * 64, j0 = bx * 64;
    float acc[4][4] = {};
    for (int k0 = 0; k0 < K_N; k0 += 16) {
        int ar = tid >> 2;            // 0..63
        int ac = (tid & 3) << 2;      // 0,4,8,12
        float4 av = *(const float4*)(We + (size_t)(v0 + ar) * K_N + k0 + ac);
        As[ac + 0][ar] = av.x; As[ac + 1][ar] = av.y;
        As[ac + 2][ar] = av.z; As[ac + 3][ar] = av.w;
        int br = tid >> 4;            // 0..15
        int bc = (tid & 15) << 2;     // 0..60
        float4 bv = *(const float4*)(Wx + (size_t)(k0 + br) * K_N + j0 + bc);
        *(float4*)&Bs[br][bc] = bv;
        __syncthreads();
#pragma unroll
        for (int kk = 0; kk < 16; kk++) {
            float a0 = As[kk][ty * 4 + 0], a1 = As[kk][ty * 4 + 1];
            float a2 = As[kk][ty * 4 + 2], a3 = As[kk][ty * 4 + 3];
            float4 bb = *(const float4*)&Bs[kk][tx * 4];
            acc[0][0] += a0 * bb.x; acc[0][1] += a0 * bb.y; acc[0][2] += a0 * bb.z; acc[0][3] += a0 * bb.w;
            acc[1][0] += a1 * bb.x; acc[1][1] += a1 * bb.y; acc[1][2] += a1 * bb.z; acc[1][3] += a1 * bb.w;
            acc[2][0] += a2 * bb.x; acc[2][1] += a2 * bb.y; acc[2][2] += a2 * bb.z; acc[2][3] += a2 * bb.w;
            acc[3][0] += a3 * bb.x; acc[3][1] += a3 * bb.y; acc[3][2] += a3 * bb.z; acc[3][3] += a3 * bb.w;
        }
        __syncthreads();
    }
    float4 bb = *(const float4*)(b + j0 + tx * 4);
#pragma unroll
    for (int i = 0; i < 4; i++) {
        float4 r;
        r.x = acc[i][0] + bb.x; r.y = acc[i][1] + bb.y;
        r.z = acc[i][2] + bb.z; r.w = acc[i][3] + bb.w;
        *(float4*)(P + (size_t)(v0 + ty * 4 + i) * K_N + j0 + tx * 4) = r;
    }
}

// ---- phase 3: single-workgroup-per-chain RNN (NO inter-WG sync) ----
// 48 blocks x 512 threads; block = (g, dir). Thread (q = tid>>7, c = tid&127)
// owns columns {4c..4c+3} over k-quarter [128q, 128q+128). Per k-row one
// float4 of Wh gives the 4 columns' weights -> all weight traffic (reg fill,
// LDS fill, per-step L2 stream) is coalesced dwordx4 from row-major Wh.
// Numerics identical to the passing kernels: mod-4 accumulators per column,
// (A+B)+(C+D), quarters reduced p0+p1+p2+p3, z = xv+sum, clamp +-15,
// tanh via __expf(2z).
__global__ __launch_bounds__(512, 2) void rnn_single(
    const float* __restrict__ P, const float* __restrict__ Wh,
    const int* __restrict__ rows, float* __restrict__ out) {

    __shared__ __align__(16) float  lds_h[K_N];                  // 2 KB
    __shared__ __align__(16) float4 Wlds4[NLDSC * 4 * 512];      // 128 KB: [row][tid]
    __shared__ __align__(16) float4 partial4[4 * 128];           // 8 KB: [q][c]

    const int tid = threadIdx.x;
    const int q   = tid >> 7;          // k-quarter
    const int c   = tid & 127;         // column group (cols 4c..4c+3)
    const int kb  = q << 7;            // k base
    const int g   = blockIdx.x >> 1;
    const int dir = blockIdx.x & 1;

    const float4* __restrict__ Wh4 = (const float4*)Wh;
    const float4* __restrict__ wbase = Wh4 + (size_t)kb * 128 + c;  // row stride 128 f4

    // one-time register tier fill (coalesced)
    float4 Wreg[NREGC * 4];
#pragma unroll
    for (int kk = 0; kk < NREGC * 4; kk++)
        Wreg[kk] = wbase[(size_t)kk * 128];
    // one-time LDS tier fill (each thread writes/reads only its own slots)
#pragma unroll
    for (int r = 0; r < NLDSC * 4; r++)
        Wlds4[r * 512 + tid] = wbase[(size_t)(NREGC * 4 + r) * 128];

    lds_h[tid] = 0.f;

    const int* __restrict__ myrows = rows + g * T_LEN;
    // x prefetch for s=0; row prefetch for s=1
    int t0 = (dir == 0) ? 0 : (T_LEN - 2);
    float xv = P[(size_t)myrows[t0] * K_N + tid];
    int t1 = (dir == 0) ? 1 : (T_LEN - 3);
    int rnxt = myrows[t1];

    const size_t outbase = (size_t)g * 1024 + (size_t)dir * 512 + tid;
    float h_prev = 0.f;
    size_t prev_addr = 0;

    __syncthreads();

    for (int s = 0; s < T_LEN; s++) {
        // staggered out-store of previous step's h: off the critical path
        if (s > 0) __builtin_nontemporal_store(h_prev, &out[prev_addr]);
        // prefetch x for s+1 (row preloaded), and row index for s+2
        float xv_next = 0.f;
        if (s + 1 < T_LEN)
            xv_next = P[(size_t)rnxt * K_N + tid];
        if (s + 2 < T_LEN) {
            int sn = s + 2;
            int tn = (dir == 0) ? sn : ((sn == T_LEN - 1) ? (T_LEN - 1) : (T_LEN - 2 - sn));
            rnxt = myrows[tn];
        }

        const float4* __restrict__ h4 = (const float4*)(lds_h + kb);  // wave-uniform
        float4 accA = {0,0,0,0}, accB = {0,0,0,0}, accC = {0,0,0,0}, accD = {0,0,0,0};
        float4 stg[LOOK][4];   // 16 float4 sliding window; i&3 compile-time after unroll

        // stream prologue: LOOK chunks in flight before first streamed use;
        // latency hides under the register/LDS-tier chunks 0..10.
#pragma unroll
        for (int i = SCH0; i < SCH0 + LOOK; i++) {
#pragma unroll
            for (int e = 0; e < 4; e++)
                stg[i & (LOOK - 1)][e] = wbase[(size_t)(4 * i + e) * 128];
        }
#pragma unroll
        for (int i = 0; i < NCHUNK; i++) {
            float4 hv = h4[i];   // uniform address -> LDS broadcast, conflict-free
            float4 w0, w1, w2, w3;
            if (i < NREGC) {                   // register tier
                w0 = Wreg[4 * i + 0]; w1 = Wreg[4 * i + 1];
                w2 = Wreg[4 * i + 2]; w3 = Wreg[4 * i + 3];
            } else if (i < SCH0) {             // LDS tier (own slots, no conflict)
                int r = (i - NREGC) * 4;
                w0 = Wlds4[(r + 0) * 512 + tid]; w1 = Wlds4[(r + 1) * 512 + tid];
                w2 = Wlds4[(r + 2) * 512 + tid]; w3 = Wlds4[(r + 3) * 512 + tid];
            } else {                           // streamed tier
                w0 = stg[i & (LOOK - 1)][0]; w1 = stg[i & (LOOK - 1)][1];
                w2 = stg[i & (LOOK - 1)][2]; w3 = stg[i & (LOOK - 1)][3];
            }
            accA.x += hv.x * w0.x; accA.y += hv.x * w0.y; accA.z += hv.x * w0.z; accA.w += hv.x * w0.w;
            accB.x += hv.y * w1.x; accB.y += hv.y * w1.y; accB.z += hv.y * w1.z; accB.w += hv.y * w1.w;
            accC.x += hv.z * w2.x; accC.y += hv.z * w2.y; accC.z += hv.z * w2.z; accC.w += hv.z * w2.w;
            accD.x += hv.w * w3.x; accD.y += hv.w * w3.y; accD.z += hv.w * w3.z; accD.w += hv.w * w3.w;
            // refill this window slot with chunk i+LOOK (steady-state stream)
            if (i >= SCH0 && i + LOOK < NCHUNK) {
#pragma unroll
                for (int e = 0; e < 4; e++)
                    stg[i & (LOOK - 1)][e] = wbase[(size_t)(4 * (i + LOOK) + e) * 128];
            }
        }
        float4 res;
        res.x = (accA.x + accB.x) + (accC.x + accD.x);
        res.y = (accA.y + accB.y) + (accC.y + accD.y);
        res.z = (accA.z + accB.z) + (accC.z + accD.z);
        res.w = (accA.w + accB.w) + (accC.w + accD.w);
        partial4[(q << 7) + c] = res;      // 16B/lane, consecutive -> conflict-free
        __syncthreads();                   // A

        // reduce: thread tid owns column j = tid
        const float* pf = (const float*)partial4;
        float p0 = pf[0 * 512 + tid], p1 = pf[1 * 512 + tid];
        float p2 = pf[2 * 512 + tid], p3 = pf[3 * 512 + tid];
        float sum = p0 + p1 + p2 + p3;
        float z = xv + sum;
        z = fminf(15.f, fmaxf(-15.f, z));
        float e2 = __expf(2.f * z);
        float h1 = 1.f - 2.f / (e2 + 1.f);                 // tanh(z)
        xv = xv_next;

        int tphys = (dir == 0) ? s : ((s == T_LEN - 1) ? (T_LEN - 1) : (T_LEN - 2 - s));
        prev_addr = (size_t)tphys * (G_N * 1024) + outbase;
        h_prev = h1;
        if (s == T_LEN - 1) break;
        lds_h[tid] = h1;                   // old h fully consumed before barrier A
        __syncthreads();                   // B: h_s visible for next step
    }
    __builtin_nontemporal_store(h_prev, &out[prev_addr]);
    __builtin_nontemporal_store(h_prev, &out[(size_t)T_LEN * (G_N * 1024) + outbase]);
}

extern "C" void kernel_launch(void* const* d_in, const int* in_sizes, int n_in,
                              void* d_out, int out_size, void* d_ws, size_t ws_size,
                              hipStream_t stream) {
    const float* seq   = (const float*)d_in[0];
    const int*   perms = (const int*)d_in[1];
    const float* We    = (const float*)d_in[2];
    const float* Wx    = (const float*)d_in[3];
    const float* Wh    = (const float*)d_in[4];
    const float* b     = (const float*)d_in[5];
    float* out = (float*)d_out;
    char* ws = (char*)d_ws;

    int*   tokens = (int*)(ws + TOK_OFF);
    int*   rows   = (int*)(ws + ROWS_OFF);
    float* P      = (float*)(ws + P_OFF);

    tok_kernel<<<512, 256, 0, stream>>>(seq, tokens);
    rows_kernel<<<(G_N * T_LEN + 255) / 256, 256, 0, stream>>>(tokens, perms, rows);
    pgemm_kernel<<<256, 256, 0, stream>>>(We, Wx, b, P);
    rnn_single<<<G_N * 2, 512, 0, stream>>>(P, Wh, rows, out);
}